// Round 2
// baseline (299.751 us; speedup 1.0000x reference)
//
#include <hip/hip_runtime.h>
#include <hip/hip_bf16.h>

// FuzzyLayer: out[b,s,d*I+i] = exp(-(x[b,s,i]-mu[d,i])^2 / sigma[d,i])
// B=16 S=2048 I=256 D=8. Output 256 MiB fp32 -> memory(write)-bound.
// R3: nontemporal loads/stores via clang ext_vector_type. Measured 295.9 us
//     (~1.0 TB/s effective -- 6x below the 6.45 TB/s the harness's own
//     fillBuffer memset achieves on this chip).
// R4: A/B the NT hint. Theory: gfx950 `nt` store flag bypasses L2 write
//     combining and collapses streaming write BW; plain stores (same path
//     as the 80%-of-peak fill) should restore it. Only change: remove
//     __builtin_nontemporal_load/store.
// R5: identical resubmit of R4 -- previous round died on container
//     acquisition (no data), so the A/B still needs to run.

#define BATCH 16
#define SEQ   2048
#define ISIZE 256
#define DEG   8
#define ROWS  (BATCH * SEQ)      // 32768 rows of x
#define ROWQ  (ISIZE / 4)        // 64 float4 per x-row
#define OUTQ  (DEG * ISIZE / 4)  // 512 float4 per out-row

typedef float f32x4 __attribute__((ext_vector_type(4)));

__device__ __forceinline__ float fast_exp2(float v) {
    return __builtin_amdgcn_exp2f(v);
}
__device__ __forceinline__ float fast_rcp(float v) {
    return __builtin_amdgcn_rcpf(v);
}

__global__ __launch_bounds__(256) void fuzzy_kernel(
    const f32x4* __restrict__ x4,
    const f32x4* __restrict__ fp4,   // (mu,sigma) interleaved pairs, 2048 pairs
    f32x4* __restrict__ out4)
{
    const int tid    = threadIdx.x;
    const int lane   = tid & 63;   // which float4 chunk of the row (i4 index)
    const int subrow = tid >> 6;   // 0..3 : row slot within the block

    // Per-thread params: 4 consecutive i values x 8 degrees, in registers.
    // fp4[j] covers (mu,sigma) pairs 2j,2j+1 -> (mu0,s0,mu1,s1).
    const float NLOG2E = -1.4426950408889634f;  // -log2(e)
    f32x4 mu[DEG], cc[DEG];
#pragma unroll
    for (int d = 0; d < DEG; ++d) {
        f32x4 p0 = fp4[d * 128 + lane * 2];
        f32x4 p1 = fp4[d * 128 + lane * 2 + 1];
        mu[d] = (f32x4){p0.x, p0.z, p1.x, p1.z};
        cc[d] = (f32x4){NLOG2E * fast_rcp(p0.y), NLOG2E * fast_rcp(p0.w),
                        NLOG2E * fast_rcp(p1.y), NLOG2E * fast_rcp(p1.w)};
    }

    // Grid-stride over groups of 4 rows (one row per 64-lane slot).
    for (int rg = blockIdx.x; rg < ROWS / 4; rg += gridDim.x) {
        const int row = rg * 4 + subrow;
        const f32x4 xv = x4[row * ROWQ + lane];
        f32x4* __restrict__ orow = out4 + (size_t)row * OUTQ + lane;
#pragma unroll
        for (int d = 0; d < DEG; ++d) {
            f32x4 o;
            float t;
            t = xv.x - mu[d].x; o.x = fast_exp2(t * t * cc[d].x);
            t = xv.y - mu[d].y; o.y = fast_exp2(t * t * cc[d].y);
            t = xv.z - mu[d].z; o.z = fast_exp2(t * t * cc[d].z);
            t = xv.w - mu[d].w; o.w = fast_exp2(t * t * cc[d].w);
            orow[d * 64] = o;
        }
    }
}

extern "C" void kernel_launch(void* const* d_in, const int* in_sizes, int n_in,
                              void* d_out, int out_size, void* d_ws, size_t ws_size,
                              hipStream_t stream) {
    const f32x4* x4  = (const f32x4*)d_in[0];
    const f32x4* fp4 = (const f32x4*)d_in[1];
    f32x4* out4      = (f32x4*)d_out;

    dim3 grid(2048);
    dim3 block(256);
    fuzzy_kernel<<<grid, block, 0, stream>>>(x4, fp4, out4);
}

// Round 3
// 296.348 us; speedup vs baseline: 1.0115x; 1.0115x over previous
//
#include <hip/hip_runtime.h>
#include <hip/hip_bf16.h>

// FuzzyLayer: out[b,s,d*I+i] = exp(-(x[b,s,i]-mu[d,i])^2 / sigma[d,i])
// B=16 S=2048 I=256 D=8. Output 256 MiB fp32 -> memory(write)-bound.
// Traffic floor: 268 MB write + 34 MB read @ 6.4 TB/s ~= 48 us.
//
// Journal:
// R3: nontemporal loads/stores. 295.9 us.
// R5: plain loads/stores (NT removed). 299.8 us -- NEUTRAL vs R3 (chip ran
//     ~3% slower that session; poison fills 166->171 us track the delta).
//     => NT hint exonerated. Also: kernel never appears in rocprof top-5
//     (all >=165 us dispatches are 1-GiB poison fills) => kernel device
//     time < ~166 us, so dur_us includes in-graph harness work (fill +
//     likely output copy). Kernel portion is somewhere in [~50, ~128] us.
// R6: attack the only remaining non-BW mechanism for the ~128 case: the
//     grid-stride loop's serial chain (load xv -> wait -> compute -> store,
//     x4, not pipelineable across dynamic loop bounds, only ~5 waves/SIMD
//     because mu/cc hold 64 VGPRs). Fully unroll the 4 row-groups: issue
//     all 4 x-loads up front (one exposed latency instead of four), then
//     straight-line compute+stores. If latency-bound: ~230-260 us. If
//     neutral: kernel is at its traffic floor -> declare roofline.

#define BATCH 16
#define SEQ   2048
#define ISIZE 256
#define DEG   8
#define ROWS  (BATCH * SEQ)      // 32768 rows of x
#define ROWQ  (ISIZE / 4)        // 64 float4 per x-row
#define OUTQ  (DEG * ISIZE / 4)  // 512 float4 per out-row
#define NBLK  2048               // grid size; 4 row-groups per block

typedef float f32x4 __attribute__((ext_vector_type(4)));

__device__ __forceinline__ float fast_exp2(float v) {
    return __builtin_amdgcn_exp2f(v);
}
__device__ __forceinline__ float fast_rcp(float v) {
    return __builtin_amdgcn_rcpf(v);
}

__global__ __launch_bounds__(256) void fuzzy_kernel(
    const f32x4* __restrict__ x4,
    const f32x4* __restrict__ fp4,   // (mu,sigma) interleaved pairs, 2048 pairs
    f32x4* __restrict__ out4)
{
    const int tid    = threadIdx.x;
    const int lane   = tid & 63;   // which float4 chunk of the row (i4 index)
    const int subrow = tid >> 6;   // 0..3 : row slot within the block

    // Per-thread params: 4 consecutive i values x 8 degrees, in registers.
    // fp4[j] covers (mu,sigma) pairs 2j,2j+1 -> (mu0,s0,mu1,s1).
    const float NLOG2E = -1.4426950408889634f;  // -log2(e)
    f32x4 mu[DEG], cc[DEG];
#pragma unroll
    for (int d = 0; d < DEG; ++d) {
        f32x4 p0 = fp4[d * 128 + lane * 2];
        f32x4 p1 = fp4[d * 128 + lane * 2 + 1];
        mu[d] = (f32x4){p0.x, p0.z, p1.x, p1.z};
        cc[d] = (f32x4){NLOG2E * fast_rcp(p0.y), NLOG2E * fast_rcp(p0.w),
                        NLOG2E * fast_rcp(p1.y), NLOG2E * fast_rcp(p1.w)};
    }

    // Each block owns 4 row-groups: b, b+NBLK, b+2*NBLK, b+3*NBLK.
    // Issue all four x-loads up front, then straight-line compute+stores.
    const int b = blockIdx.x;
    int row[4];
    f32x4 xv[4];
#pragma unroll
    for (int k = 0; k < 4; ++k) {
        row[k] = (b + k * NBLK) * 4 + subrow;
        xv[k]  = x4[row[k] * ROWQ + lane];
    }

#pragma unroll
    for (int k = 0; k < 4; ++k) {
        f32x4* __restrict__ orow = out4 + (size_t)row[k] * OUTQ + lane;
        const f32x4 xk = xv[k];
#pragma unroll
        for (int d = 0; d < DEG; ++d) {
            f32x4 o;
            float t;
            t = xk.x - mu[d].x; o.x = fast_exp2(t * t * cc[d].x);
            t = xk.y - mu[d].y; o.y = fast_exp2(t * t * cc[d].y);
            t = xk.z - mu[d].z; o.z = fast_exp2(t * t * cc[d].z);
            t = xk.w - mu[d].w; o.w = fast_exp2(t * t * cc[d].w);
            orow[d * 64] = o;
        }
    }
}

extern "C" void kernel_launch(void* const* d_in, const int* in_sizes, int n_in,
                              void* d_out, int out_size, void* d_ws, size_t ws_size,
                              hipStream_t stream) {
    const f32x4* x4  = (const f32x4*)d_in[0];
    const f32x4* fp4 = (const f32x4*)d_in[1];
    f32x4* out4      = (f32x4*)d_out;

    dim3 grid(NBLK);
    dim3 block(256);
    fuzzy_kernel<<<grid, block, 0, stream>>>(x4, fp4, out4);
}